// Round 8
// baseline (533.617 us; speedup 1.0000x reference)
//
#include <hip/hip_runtime.h>

using f16 = _Float16;
using half8  = __attribute__((ext_vector_type(8))) f16;
using half4v = __attribute__((ext_vector_type(4))) f16;
using float4v = __attribute__((ext_vector_type(4))) float;

#define DEV static __device__ __forceinline__

constexpr int N = 2048, DIM = 1024, H = 16, DH = 64, F6 = 6144;
constexpr int LDSH = 136;       // f16 epilogue row stride (halves)
constexpr int TS = 128 * 128;   // packed tile elements
constexpr int NTILES = 136;     // triangular 128x128 tiles per head

DEV int PL(int i, int k) { return i * (i + 1) / 2 + k; }  // lower-tri tile index, k<=i

template<int ROWS, int THREADS>
DEV void stage64(const f16* __restrict__ g, int strideHalves, f16* lds, int tid) {
#pragma unroll
  for (int q = 0; q < (ROWS * 8) / THREADS; ++q) {
    const int chunk = q * THREADS + tid;
    const int m = chunk >> 3, c = (chunk & 7) ^ (m & 7);
    const f16* gp = g + (size_t)m * strideHalves + c * 8;
    __builtin_amdgcn_global_load_lds(
        (const __attribute__((address_space(1))) unsigned int*)gp,
        (__attribute__((address_space(3))) unsigned int*)(lds + chunk * 8), 16, 0, 0);
  }
}

DEV half8 rdfrag(const f16* T, int m, int ks, int q) {
  const int c = (ks * 4 + q) ^ (m & 7);
  return *(const half8*)(T + m * 64 + c * 8);
}

// store one element into frag layout (inverse of rdfrag addressing)
DEV void wfrag(f16* T, int row, int col, f16 v) {
  T[row * 64 + ((((col >> 3) ^ (row & 7)) << 3) | (col & 7))] = v;
}

DEV void gemm64(const f16* As, const f16* Bs, int wm, int wn, int l, float4v acc[4][4]) {
  const int q = l >> 4, mm = l & 15;
#pragma unroll
  for (int ks = 0; ks < 2; ++ks) {
    half8 af[4], bf[4];
#pragma unroll
    for (int mi = 0; mi < 4; ++mi) af[mi] = rdfrag(As, wm + mm + mi * 16, ks, q);
#pragma unroll
    for (int ni = 0; ni < 4; ++ni) bf[ni] = rdfrag(Bs, wn + mm + ni * 16, ks, q);
#pragma unroll
    for (int mi = 0; mi < 4; ++mi)
#pragma unroll
      for (int ni = 0; ni < 4; ++ni)
        acc[mi][ni] = __builtin_amdgcn_mfma_f32_16x16x32_f16(af[mi], bf[ni], acc[mi][ni], 0, 0, 0);
  }
}

template<int ROWS, int THREADS>
DEV void flush(const f16* lds, f16* __restrict__ g, int strideHalves, int tid) {
  __syncthreads();
#pragma unroll
  for (int q = 0; q < ROWS * 16 / THREADS; ++q) {
    const int idx = q * THREADS + tid, row = idx >> 4, c = idx & 15;
    *(half8*)(g + (size_t)row * strideHalves + c * 8) = *(const half8*)(lds + row * LDSH + c * 8);
  }
  __syncthreads();
}

// p in [0,136) -> (ti,tk), tk<=ti, ordered longest-K-first (ti-tk descending).
DEV void decode_pair(int p, int& ti, int& tk) {
  int t = (int)((sqrtf(8.f * p + 1.f) - 1.f) * 0.5f);
  while (t * (t + 1) / 2 > p) --t;
  while ((t + 1) * (t + 2) / 2 <= p) ++t;
  const int i2 = p - t * (t + 1) / 2;
  ti = (15 - t) + i2;
  tk = i2;
}

__global__ __launch_bounds__(256) void k_cast(const float* __restrict__ s, f16* __restrict__ d, int n4) {
  int i = blockIdx.x * 256 + threadIdx.x;
  if (i < n4) {
    float4 v = ((const float4*)s)[i];
    half4v h;
    h[0] = (f16)v.x; h[1] = (f16)v.y; h[2] = (f16)v.z; h[3] = (f16)v.w;
    ((half4v*)d)[i] = h;
  }
}

// qkvs = x @ w_qkv^T; per-head scatter (block-uniform slot t).
__global__ __launch_bounds__(256) void k_qkv(const f16* __restrict__ xh, const f16* __restrict__ wh,
                                             f16* __restrict__ quh, f16* __restrict__ kuh,
                                             f16* __restrict__ vuh, f16* __restrict__ qch,
                                             f16* __restrict__ kch, f16* __restrict__ vcT) {
  __shared__ __align__(16) f16 lds[128 * LDSH];
  f16* As = lds; f16* Bs = lds + 128 * 64;
  const int tid = threadIdx.x, w = tid >> 6, l = tid & 63;
  const int tm = blockIdx.x * 128, tf = blockIdx.y * 128;
  const int wm = (w >> 1) * 64, wn = (w & 1) * 64;
  float4v acc[4][4] = {};
  for (int k0 = 0; k0 < DIM; k0 += 64) {
    stage64<128, 256>(xh + (size_t)tm * DIM + k0, DIM, As, tid);
    stage64<128, 256>(wh + (size_t)tf * DIM + k0, DIM, Bs, tid);
    __syncthreads();
    gemm64(As, Bs, wm, wn, l, acc);
    __syncthreads();
  }
  const int rbase = (l >> 4) * 4, cidx = l & 15;
  const int t = tf >> 10;
  const float sc = (t == 0 || t == 3) ? 0.125f : 1.f;
  if (t == 5) {
#pragma unroll
    for (int mi = 0; mi < 4; ++mi)
#pragma unroll
      for (int ni = 0; ni < 4; ++ni) {
        const int f = tf + wn + ni * 16 + cidx;
        const int h = (f & 1023) >> 6, d = f & 63;
        half4v p;
#pragma unroll
        for (int r = 0; r < 4; ++r) p[r] = (f16)acc[mi][ni][r];
        *(half4v*)(vcT + ((size_t)h * DH + d) * N + (tm + wm + mi * 16 + rbase)) = p;
      }
  } else {
#pragma unroll
    for (int mi = 0; mi < 4; ++mi)
#pragma unroll
      for (int ni = 0; ni < 4; ++ni)
#pragma unroll
        for (int r = 0; r < 4; ++r)
          lds[(wm + mi * 16 + rbase + r) * LDSH + wn + ni * 16 + cidx] = (f16)(acc[mi][ni][r] * sc);
    __syncthreads();
    f16* dst = (t == 0) ? quh : (t == 1) ? kuh : (t == 2) ? vuh : (t == 3) ? qch : kch;
    const int hb = (tf & 1023) >> 6;
#pragma unroll
    for (int q = 0; q < 8; ++q) {
      const int idx = q * 256 + tid, row = idx >> 4, c = idx & 15;
      const int h = hb + (c >> 3), d0 = (c & 7) * 8, n = tm + row;
      *(half8*)(dst + ((size_t)h * N + n) * DH + d0) = *(const half8*)(lds + row * LDSH + c * 8);
    }
  }
}

// Fused scores kernel: scob(ti,tk) = qc.kc^T - silu( tril(qc.vu^T) @ triu1(sigmoid(qu.ku^T))^T )
// term1/sig 128x64 chunks generated ON THE FLY in LDS from qc/qu (A-frag, staged once)
// x vu/ku (16KB/chunk — half the bytes of materialized tiles; per-head inputs ~1.3MB
// stay L2-resident with head->XCD pinning via blockIdx.x). 2 barriers/chunk; stage of
// chunk c+1 overlaps the Su MFMA step of chunk c.
__global__ __launch_bounds__(256) void k_fsu(const f16* __restrict__ qch, const f16* __restrict__ quh,
                                             const f16* __restrict__ vuh, const f16* __restrict__ kuh,
                                             const f16* __restrict__ kch, f16* __restrict__ scob, int h0) {
  __shared__ __align__(16) f16 L[40960];  // 80KB -> 2 blocks/CU
  f16* qcA = L;           // 128x64 A-frag: qc[ti]
  f16* quA = L + 8192;    // 128x64 A-frag: qu[tk]
  f16* vuB = L + 16384;   // 64x64
  f16* kuB = L + 20480;   // 64x64
  f16* t1s = L + 24576;   // 128x64 generated term1 chunk (also reused for kc in Sc phase)
  f16* sgs = L + 32768;   // 128x64 generated sig chunk
  f16* eps = L + 16384;   // epilogue overlay (128*LDSH = 17408 halves)

  int ti, tk;
  decode_pair(blockIdx.y, ti, tk);
  const int hl = blockIdx.x;
  const int tid = threadIdx.x, w = tid >> 6, l = tid & 63;
  const int q = l >> 4, m = l & 15;
  const int wm = (w >> 1) * 64, wn = (w & 1) * 64;
  const size_t ho = (size_t)(h0 + hl) * N * DH;
  const f16* qc = qch + ho; const f16* qu = quh + ho;
  const f16* vu = vuh + ho; const f16* ku = kuh + ho;

  stage64<128, 256>(qc + (size_t)(ti * 128) * DH, DH, qcA, tid);
  stage64<128, 256>(qu + (size_t)(tk * 128) * DH, DH, quA, tid);
  stage64<64, 256>(vu + (size_t)(tk * 128) * DH, DH, vuB, tid);
  stage64<64, 256>(ku + (size_t)(tk * 128) * DH, DH, kuB, tid);
  __syncthreads();

  const int gr0 = (w & 1) * 64, gc0 = (w >> 1) * 32;  // gen quadrant: 64 rows x 32 cols
  const int i0 = ti * 128, k0r = tk * 128;
  float4v acc[4][4] = {};
  const int jend = (ti + 1) * 128;

  // gen(j0): build term1/sig chunks for columns [j0, j0+64) into t1s/sgs
  auto gen = [&](int j0) {
    float4v a1[4][2] = {}, a2[4][2] = {};
#pragma unroll
    for (int ks = 0; ks < 2; ++ks) {
      half8 af[4], bf[2], af2[4], bf2[2];
#pragma unroll
      for (int mi = 0; mi < 4; ++mi) af[mi] = rdfrag(qcA, gr0 + mi * 16 + m, ks, q);
#pragma unroll
      for (int ni = 0; ni < 2; ++ni) bf[ni] = rdfrag(vuB, gc0 + ni * 16 + m, ks, q);
#pragma unroll
      for (int mi = 0; mi < 4; ++mi) af2[mi] = rdfrag(quA, gr0 + mi * 16 + m, ks, q);
#pragma unroll
      for (int ni = 0; ni < 2; ++ni) bf2[ni] = rdfrag(kuB, gc0 + ni * 16 + m, ks, q);
#pragma unroll
      for (int mi = 0; mi < 4; ++mi)
#pragma unroll
        for (int ni = 0; ni < 2; ++ni) {
          a1[mi][ni] = __builtin_amdgcn_mfma_f32_16x16x32_f16(af[mi], bf[ni], a1[mi][ni], 0, 0, 0);
          a2[mi][ni] = __builtin_amdgcn_mfma_f32_16x16x32_f16(af2[mi], bf2[ni], a2[mi][ni], 0, 0, 0);
        }
    }
#pragma unroll
    for (int mi = 0; mi < 4; ++mi)
#pragma unroll
      for (int ni = 0; ni < 2; ++ni)
#pragma unroll
        for (int r = 0; r < 4; ++r) {
          const int row = gr0 + mi * 16 + q * 4 + r;
          const int col = gc0 + ni * 16 + m;
          const int jg = j0 + col;
          wfrag(t1s, row, col, (jg <= i0 + row) ? (f16)a1[mi][ni][r] : (f16)0.f);
          const float x = a2[mi][ni][r];
          wfrag(sgs, row, col, (jg > k0r + row) ? (f16)(1.f / (1.f + __expf(-x))) : (f16)0.f);
        }
  };

  gen(tk * 128);
  for (int jc = tk * 128 + 64; jc < jend; jc += 64) {
    __syncthreads();                                     // gen visible; vuB/kuB free
    stage64<64, 256>(vu + (size_t)jc * DH, DH, vuB, tid);  // async, consumed after next barrier
    stage64<64, 256>(ku + (size_t)jc * DH, DH, kuB, tid);
    gemm64(t1s, sgs, wm, wn, l, acc);                    // Su step for previous chunk
    __syncthreads();                                     // stages drained; t1s/sgs free
    gen(jc);
  }
  __syncthreads();
  gemm64(t1s, sgs, wm, wn, l, acc);  // last chunk
#pragma unroll
  for (int mi = 0; mi < 4; ++mi)
#pragma unroll
    for (int ni = 0; ni < 4; ++ni)
#pragma unroll
      for (int r = 0; r < 4; ++r) {
        const float x = acc[mi][ni][r];
        acc[mi][ni][r] = -(x / (1.f + __expf(-x)));  // -silu(Su)
      }
  __syncthreads();  // all waves done reading t1s
  stage64<128, 256>(kch + ho + (size_t)(tk * 128) * DH, DH, t1s, tid);  // kc -> t1s slot
  __syncthreads();
  gemm64(qcA, t1s, wm, wn, l, acc);  // acc = Sc - silu(Su)
  __syncthreads();

  const int rbase = q * 4;
#pragma unroll
  for (int mi = 0; mi < 4; ++mi)
#pragma unroll
    for (int ni = 0; ni < 4; ++ni)
#pragma unroll
      for (int r = 0; r < 4; ++r)
        eps[(wm + mi * 16 + rbase + r) * LDSH + wn + ni * 16 + m] = (f16)acc[mi][ni][r];
  flush<128, 256>(eps, scob + ((size_t)hl * NTILES + PL(ti, tk)) * TS, 128, tid);
}

// Fused softmax(scores) @ vc with flash-style online softmax over packed score
// tiles. blockIdx.x = head (XCD pinning); 4 waves split j-tiles, merged via LDS.
__global__ __launch_bounds__(256) void k_avs(const f16* __restrict__ scob, const f16* __restrict__ vcT,
                                             f16* __restrict__ Oh, int h0) {
  __shared__ float mlds[4][32], llds[4][32];
  __shared__ __align__(16) float olds[32][68];
  const int hl = blockIdx.x, h = h0 + hl;
  const int mt = 63 - (int)blockIdx.y;  // longest-first
  const int tid = threadIdx.x, w = tid >> 6, l = tid & 63;
  const int q = l >> 4, m = l & 15;
  const f16* Sh = scob + (size_t)hl * NTILES * TS;
  const int titile = mt >> 2, irb = (mt & 3) * 32;
  const f16* V = vcT + (size_t)h * DH * N;
  int vrow[4];
#pragma unroll
  for (int ni = 0; ni < 4; ++ni) vrow[ni] = (ni * 16 + m) * N + q * 8;
  float4v o[2][4] = {};
  float mrun[2] = {-1e30f, -1e30f}, lrun[2] = {0.f, 0.f};
  const int jtmax = mt >> 1;  // inclusive; diagonal tile == jtmax
  for (int jt = w; jt <= jtmax; jt += 4) {
    const int j0 = jt * 64;
    const f16* Sbase = Sh + (size_t)PL(titile, jt >> 1) * TS + (jt & 1) * 64;
    float alphav[2];
    half8 pf[2][2];
#pragma unroll
    for (int mi = 0; mi < 2; ++mi) {
      half8 sf[2];
#pragma unroll
      for (int ks = 0; ks < 2; ++ks)
        sf[ks] = *(const half8*)(Sbase + (irb + mi * 16 + m) * 128 + ks * 32 + q * 8);
      const int rowg = mt * 32 + mi * 16 + m;
      float vals[16];
      float tmx = -1e30f;
#pragma unroll
      for (int ks = 0; ks < 2; ++ks)
#pragma unroll
        for (int e = 0; e < 8; ++e) {
          const int col = j0 + ks * 32 + q * 8 + e;
          const float x = (jt < jtmax || col <= rowg) ? (float)sf[ks][e] : -1e30f;
          vals[ks * 8 + e] = x;
          tmx = fmaxf(tmx, x);
        }
      tmx = fmaxf(tmx, __shfl_xor(tmx, 16));
      tmx = fmaxf(tmx, __shfl_xor(tmx, 32));
      const float nm = fmaxf(mrun[mi], tmx);
      const float al = __expf(mrun[mi] - nm);
      float ts = 0.f;
#pragma unroll
      for (int ks = 0; ks < 2; ++ks)
#pragma unroll
        for (int e = 0; e < 8; ++e) {
          const float p = __expf(vals[ks * 8 + e] - nm);
          pf[mi][ks][e] = (f16)p;
          ts += p;
        }
      ts += __shfl_xor(ts, 16);
      ts += __shfl_xor(ts, 32);
      lrun[mi] = lrun[mi] * al + ts;
      mrun[mi] = nm;
      alphav[mi] = al;
    }
#pragma unroll
    for (int mi = 0; mi < 2; ++mi)
#pragma unroll
      for (int r = 0; r < 4; ++r) {
        const float a = __shfl(alphav[mi], q * 4 + r);
#pragma unroll
        for (int ni = 0; ni < 4; ++ni) o[mi][ni][r] *= a;
      }
#pragma unroll
    for (int ni = 0; ni < 4; ++ni)
#pragma unroll
      for (int ks = 0; ks < 2; ++ks) {
        half8 vf = *(const half8*)(V + vrow[ni] + j0 + ks * 32);
#pragma unroll
        for (int mi = 0; mi < 2; ++mi)
          o[mi][ni] = __builtin_amdgcn_mfma_f32_16x16x32_f16(pf[mi][ks], vf, o[mi][ni], 0, 0, 0);
      }
  }
  if (l < 16)
#pragma unroll
    for (int mi = 0; mi < 2; ++mi) {
      mlds[w][mi * 16 + l] = mrun[mi];
      llds[w][mi * 16 + l] = lrun[mi];
    }
  __syncthreads();
#pragma unroll
  for (int mi = 0; mi < 2; ++mi)
#pragma unroll
    for (int r = 0; r < 4; ++r) {
      const int row = mi * 16 + q * 4 + r;
      const float mstar = fmaxf(fmaxf(mlds[0][row], mlds[1][row]), fmaxf(mlds[2][row], mlds[3][row]));
      const float sw = __expf(mlds[w][row] - mstar);
#pragma unroll
      for (int ni = 0; ni < 4; ++ni) o[mi][ni][r] *= sw;
    }
#pragma unroll
  for (int t = 0; t < 4; ++t) {
    if (w == t) {
#pragma unroll
      for (int mi = 0; mi < 2; ++mi)
#pragma unroll
        for (int ni = 0; ni < 4; ++ni)
#pragma unroll
          for (int r = 0; r < 4; ++r) {
            const int row = mi * 16 + q * 4 + r, col = ni * 16 + m;
            if (t == 0) olds[row][col] = o[mi][ni][r];
            else olds[row][col] += o[mi][ni][r];
          }
    }
    __syncthreads();
  }
  const int row = tid >> 3, c = tid & 7;
  const float mstar = fmaxf(fmaxf(mlds[0][row], mlds[1][row]), fmaxf(mlds[2][row], mlds[3][row]));
  float denom = 0.f;
#pragma unroll
  for (int t = 0; t < 4; ++t) denom += __expf(mlds[t][row] - mstar) * llds[t][row];
  const float inv = 1.f / denom;
  half8 o8;
#pragma unroll
  for (int e = 0; e < 8; ++e) o8[e] = (f16)(olds[row][c * 8 + e] * inv);
  *(half8*)(Oh + (size_t)(mt * 32 + row) * (H * DH) + h * DH + c * 8) = o8;
}

// out = O @ w_out^T, fp32 result.
__global__ __launch_bounds__(256) void k_out(const f16* __restrict__ Oh, const f16* __restrict__ wo,
                                             float* __restrict__ out) {
  __shared__ __align__(16) f16 lds[128 * LDSH];
  f16* As = lds; f16* Bs = lds + 128 * 64;
  const int tid = threadIdx.x, w = tid >> 6, l = tid & 63;
  const int tm = blockIdx.x * 128, tn = blockIdx.y * 128;
  const int wm = (w >> 1) * 64, wn = (w & 1) * 64;
  float4v acc[4][4] = {};
  for (int k0 = 0; k0 < DIM; k0 += 64) {
    stage64<128, 256>(Oh + (size_t)tm * DIM + k0, DIM, As, tid);
    stage64<128, 256>(wo + (size_t)tn * DIM + k0, DIM, Bs, tid);
    __syncthreads();
    gemm64(As, Bs, wm, wn, l, acc);
    __syncthreads();
  }
  const int rbase = (l >> 4) * 4, cidx = l & 15;
#pragma unroll
  for (int mi = 0; mi < 4; ++mi)
#pragma unroll
    for (int ni = 0; ni < 4; ++ni)
#pragma unroll
      for (int r = 0; r < 4; ++r) {
        const int n = tm + wm + mi * 16 + rbase + r;
        const int dmo = tn + wn + ni * 16 + cidx;
        out[(size_t)n * DIM + dmo] = acc[mi][ni][r];
      }
}

extern "C" void kernel_launch(void* const* d_in, const int* in_sizes, int n_in,
                              void* d_out, int out_size, void* d_ws, size_t ws_size,
                              hipStream_t stream) {
  const float* x = (const float*)d_in[0];
  const float* wqkv = (const float*)d_in[1];
  const float* wout = (const float*)d_in[2];
  float* out = (float*)d_out;
  char* ws = (char*)d_ws;

  size_t off = 0;
  auto alloc = [&](size_t b) { size_t o = off; off += (b + 255) & ~(size_t)255; return o; };
  f16* xh  = (f16*)(ws + alloc((size_t)N * DIM * 2));
  f16* wqh = (f16*)(ws + alloc((size_t)F6 * DIM * 2));
  f16* woh = (f16*)(ws + alloc((size_t)DIM * H * DH * 2));
  f16* quh = (f16*)(ws + alloc((size_t)H * N * DH * 2));
  f16* kuh = (f16*)(ws + alloc((size_t)H * N * DH * 2));
  f16* vuh = (f16*)(ws + alloc((size_t)H * N * DH * 2));
  f16* qch = (f16*)(ws + alloc((size_t)H * N * DH * 2));
  f16* kch = (f16*)(ws + alloc((size_t)H * N * DH * 2));
  f16* vcT = (f16*)(ws + alloc((size_t)H * DH * N * 2));
  f16* Oh  = (f16*)(ws + alloc((size_t)N * H * DH * 2));
  const size_t persist = off;

  // packed triangular score tiles only: 136 x 32KB per head
  const size_t per_head = (size_t)NTILES * TS * 2;
  int G = (ws_size > persist + 4096) ? (int)((ws_size - persist - 4096) / per_head) : 1;
  if (G < 1) G = 1;
  if (G > 16) G = 16;
  {  // normalize so rounds are evenly sized
    const int R = (H + G - 1) / G;
    G = (H + R - 1) / R;
  }
  f16* scob = (f16*)(ws + alloc((size_t)G * NTILES * TS * 2));

  k_cast<<<(N * DIM / 4 + 255) / 256, 256, 0, stream>>>(x, xh, N * DIM / 4);
  k_cast<<<(F6 * DIM / 4 + 255) / 256, 256, 0, stream>>>(wqkv, wqh, F6 * DIM / 4);
  k_cast<<<(DIM * H * DH / 4 + 255) / 256, 256, 0, stream>>>(wout, woh, DIM * H * DH / 4);

  k_qkv<<<dim3(N / 128, F6 / 128), 256, 0, stream>>>(xh, wqh, quh, kuh, vuh, qch, kch, vcT);

  for (int h0 = 0; h0 < H; h0 += G) {
    const int Gr = (H - h0 < G) ? (H - h0) : G;
    k_fsu<<<dim3(Gr, 136), 256, 0, stream>>>(qch, quh, vuh, kuh, kch, scob, h0);
    k_avs<<<dim3(Gr, 64), 256, 0, stream>>>(scob, vcT, Oh, h0);
  }

  k_out<<<dim3(16, 8), 256, 0, stream>>>(Oh, woh, out);
}

// Round 9
// 339.798 us; speedup vs baseline: 1.5704x; 1.5704x over previous
//
#include <hip/hip_runtime.h>

using f16 = _Float16;
using half8  = __attribute__((ext_vector_type(8))) f16;
using half4v = __attribute__((ext_vector_type(4))) f16;
using float4v = __attribute__((ext_vector_type(4))) float;

#define DEV static __device__ __forceinline__

constexpr int N = 2048, DIM = 1024, H = 16, DH = 64, F6 = 6144;
constexpr int LDSH = 136;       // f16 epilogue row stride (halves)
constexpr int TS = 128 * 128;   // packed tile elements
constexpr int NTILES = 136;     // triangular 128x128 tiles per head
constexpr int KD = 2048 * 64;   // D/C elements per T-slice per head

DEV int PL(int i, int k) { return i * (i + 1) / 2 + k; }                  // lower, k<=i
DEV int PU(int a, int b) { return a * 16 - a * (a - 1) / 2 + (b - a); }   // upper, a<=b

template<int ROWS, int THREADS>
DEV void stage64(const f16* __restrict__ g, int strideHalves, f16* lds, int tid) {
#pragma unroll
  for (int q = 0; q < (ROWS * 8) / THREADS; ++q) {
    const int chunk = q * THREADS + tid;
    const int m = chunk >> 3, c = (chunk & 7) ^ (m & 7);
    const f16* gp = g + (size_t)m * strideHalves + c * 8;
    __builtin_amdgcn_global_load_lds(
        (const __attribute__((address_space(1))) unsigned int*)gp,
        (__attribute__((address_space(3))) unsigned int*)(lds + chunk * 8), 16, 0, 0);
  }
}

DEV half8 rdfrag(const f16* T, int m, int ks, int q) {
  const int c = (ks * 4 + q) ^ (m & 7);
  return *(const half8*)(T + m * 64 + c * 8);
}

// store one element into frag layout (inverse of rdfrag addressing)
DEV void wfrag(f16* T, int row, int col, f16 v) {
  T[row * 64 + ((((col >> 3) ^ (row & 7)) << 3) | (col & 7))] = v;
}

DEV void gemm64(const f16* As, const f16* Bs, int wm, int wn, int l, float4v acc[4][4]) {
  const int q = l >> 4, mm = l & 15;
#pragma unroll
  for (int ks = 0; ks < 2; ++ks) {
    half8 af[4], bf[4];
#pragma unroll
    for (int mi = 0; mi < 4; ++mi) af[mi] = rdfrag(As, wm + mm + mi * 16, ks, q);
#pragma unroll
    for (int ni = 0; ni < 4; ++ni) bf[ni] = rdfrag(Bs, wn + mm + ni * 16, ks, q);
#pragma unroll
    for (int mi = 0; mi < 4; ++mi)
#pragma unroll
      for (int ni = 0; ni < 4; ++ni)
        acc[mi][ni] = __builtin_amdgcn_mfma_f32_16x16x32_f16(af[mi], bf[ni], acc[mi][ni], 0, 0, 0);
  }
}

template<int ROWS, int THREADS>
DEV void flush(const f16* lds, f16* __restrict__ g, int strideHalves, int tid) {
  __syncthreads();
#pragma unroll
  for (int q = 0; q < ROWS * 16 / THREADS; ++q) {
    const int idx = q * THREADS + tid, row = idx >> 4, c = idx & 15;
    *(half8*)(g + (size_t)row * strideHalves + c * 8) = *(const half8*)(lds + row * LDSH + c * 8);
  }
  __syncthreads();
}

// p in [0,136) -> (ti,tk), tk<=ti.
DEV void decode_pair(int p, int& ti, int& tk) {
  int t = (int)((sqrtf(8.f * p + 1.f) - 1.f) * 0.5f);
  while (t * (t + 1) / 2 > p) --t;
  while ((t + 1) * (t + 2) / 2 <= p) ++t;
  const int i2 = p - t * (t + 1) / 2;
  ti = (15 - t) + i2;
  tk = i2;
}

__global__ __launch_bounds__(256) void k_cast(const float* __restrict__ s, f16* __restrict__ d, int n4) {
  int i = blockIdx.x * 256 + threadIdx.x;
  if (i < n4) {
    float4 v = ((const float4*)s)[i];
    half4v h;
    h[0] = (f16)v.x; h[1] = (f16)v.y; h[2] = (f16)v.z; h[3] = (f16)v.w;
    ((half4v*)d)[i] = h;
  }
}

// qkvs = x @ w_qkv^T; per-head scatter. vu additionally stored transposed (vuT[h][d][n])
// for the D-GEMM's B-operand; vc stored transposed only.
__global__ __launch_bounds__(256) void k_qkv(const f16* __restrict__ xh, const f16* __restrict__ wh,
                                             f16* __restrict__ quh, f16* __restrict__ kuh,
                                             f16* __restrict__ vuh, f16* __restrict__ qch,
                                             f16* __restrict__ kch, f16* __restrict__ vcT,
                                             f16* __restrict__ vuT) {
  __shared__ __align__(16) f16 lds[128 * LDSH];
  f16* As = lds; f16* Bs = lds + 128 * 64;
  const int tid = threadIdx.x, w = tid >> 6, l = tid & 63;
  const int tm = blockIdx.x * 128, tf = blockIdx.y * 128;
  const int wm = (w >> 1) * 64, wn = (w & 1) * 64;
  float4v acc[4][4] = {};
  for (int k0 = 0; k0 < DIM; k0 += 64) {
    stage64<128, 256>(xh + (size_t)tm * DIM + k0, DIM, As, tid);
    stage64<128, 256>(wh + (size_t)tf * DIM + k0, DIM, Bs, tid);
    __syncthreads();
    gemm64(As, Bs, wm, wn, l, acc);
    __syncthreads();
  }
  const int rbase = (l >> 4) * 4, cidx = l & 15;
  const int t = tf >> 10;
  const float sc = (t == 0 || t == 3) ? 0.125f : 1.f;
  if (t == 5 || t == 2) {
    f16* T = (t == 5) ? vcT : vuT;
#pragma unroll
    for (int mi = 0; mi < 4; ++mi)
#pragma unroll
      for (int ni = 0; ni < 4; ++ni) {
        const int f = tf + wn + ni * 16 + cidx;
        const int h = (f & 1023) >> 6, d = f & 63;
        half4v p;
#pragma unroll
        for (int r = 0; r < 4; ++r) p[r] = (f16)acc[mi][ni][r];
        *(half4v*)(T + ((size_t)h * DH + d) * N + (tm + wm + mi * 16 + rbase)) = p;
      }
  }
  if (t != 5) {
#pragma unroll
    for (int mi = 0; mi < 4; ++mi)
#pragma unroll
      for (int ni = 0; ni < 4; ++ni)
#pragma unroll
        for (int r = 0; r < 4; ++r)
          lds[(wm + mi * 16 + rbase + r) * LDSH + wn + ni * 16 + cidx] = (f16)(acc[mi][ni][r] * sc);
    __syncthreads();
    f16* dst = (t == 0) ? quh : (t == 1) ? kuh : (t == 2) ? vuh : (t == 3) ? qch : kch;
    const int hb = (tf & 1023) >> 6;
#pragma unroll
    for (int q = 0; q < 8; ++q) {
      const int idx = q * 256 + tid, row = idx >> 4, c = idx & 15;
      const int h = hb + (c >> 3), d0 = (c & 7) * 8, n = tm + row;
      *(half8*)(dst + ((size_t)h * N + n) * DH + d0) = *(const half8*)(lds + row * LDSH + c * 8);
    }
  }
}

// Per pair (a<=b): sig tile PU(a,b) = triu1(sigmoid(qu[a].ku[b]^T)), computed ONCE;
// fused D-contribution D^{(b)}[a-rows] = sigtile @ vu[b-block]; for a==b also the
// diagonal term1 tile tril(qc[a].vu[a]^T) (the only term1 tiles the new k_su needs).
__global__ __launch_bounds__(256) void k_dsig(const f16* __restrict__ quh, const f16* __restrict__ kuh,
                                              const f16* __restrict__ qch, const f16* __restrict__ vuh,
                                              const f16* __restrict__ vuT,
                                              f16* __restrict__ sigb, f16* __restrict__ DC,
                                              f16* __restrict__ diagb, int h0) {
  __shared__ __align__(16) f16 L[32768];  // quA 8192 | kuB 8192 (reused vtB0/vtB1) | s1 8192 | s2 8192
  f16* quA = L; f16* kuB = L + 8192; f16* s1 = L + 16384; f16* s2 = L + 24576;
  int b, a;
  decode_pair(blockIdx.x, b, a);
  const int hl = blockIdx.y, h = h0 + hl;
  const int tid = threadIdx.x, w = tid >> 6, l = tid & 63;
  const int q = l >> 4, m = l & 15;
  const int wm = (w >> 1) * 64, wn = (w & 1) * 64;
  const size_t ho = (size_t)h * N * DH;

  stage64<128, 256>(quh + ho + (size_t)(a * 128) * DH, DH, quA, tid);
  stage64<128, 256>(kuh + ho + (size_t)(b * 128) * DH, DH, kuB, tid);
  __syncthreads();
  float4v acc[4][4] = {};
  gemm64(quA, kuB, wm, wn, l, acc);  // qu[a] . ku[b]^T
  __syncthreads();  // quA/kuB reads done
  // stage vuT chunks (B-operand for D) into kuB space
  stage64<64, 256>(vuT + (size_t)h * DH * N + b * 128, N, kuB, tid);
  stage64<64, 256>(vuT + (size_t)h * DH * N + b * 128 + 64, N, kuB + 4096, tid);
  // sigmoid + strict-upper mask -> swizzled A-frag panels s1/s2
#pragma unroll
  for (int mi = 0; mi < 4; ++mi)
#pragma unroll
    for (int ni = 0; ni < 4; ++ni)
#pragma unroll
      for (int r = 0; r < 4; ++r) {
        const int row = wm + mi * 16 + q * 4 + r;   // k-local
        const int col = wn + ni * 16 + m;           // j-local
        const float x = acc[mi][ni][r];
        const f16 sv = (b * 128 + col > a * 128 + row) ? (f16)(1.f / (1.f + __expf(-x))) : (f16)0.f;
        wfrag((col < 64) ? s1 : s2, row, col & 63, sv);
      }
  __syncthreads();  // panels visible; vtB staged
  // flush sig panels -> global PU tile (row-major, stride 128)
  {
    f16* Sg = sigb + ((size_t)hl * NTILES + PU(a, b)) * TS;
#pragma unroll
    for (int qq = 0; qq < 8; ++qq) {
      const int idx = qq * 256 + tid, row = idx >> 4, c = idx & 15;
      const f16* p = ((c >> 3) ? s2 : s1) + row * 64 + (((c & 7) ^ (row & 7)) << 3);
      *(half8*)(Sg + (size_t)row * 128 + c * 8) = *(const half8*)p;
    }
  }
  // D gemm: D[k,d] = sum_j sig[k,j] vu[j,d]; wave w covers k-rows [w*32, w*32+32)
  float4v dacc[2][4] = {};
#pragma unroll
  for (int p = 0; p < 2; ++p)
#pragma unroll
    for (int ks = 0; ks < 2; ++ks) {
      half8 bf[4], af[2];
#pragma unroll
      for (int ni = 0; ni < 4; ++ni) bf[ni] = rdfrag(kuB + p * 4096, ni * 16 + m, ks, q);
#pragma unroll
      for (int mi = 0; mi < 2; ++mi) af[mi] = rdfrag(p ? s2 : s1, w * 32 + mi * 16 + m, ks, q);
#pragma unroll
      for (int mi = 0; mi < 2; ++mi)
#pragma unroll
        for (int ni = 0; ni < 4; ++ni)
          dacc[mi][ni] = __builtin_amdgcn_mfma_f32_16x16x32_f16(af[mi], bf[ni], dacc[mi][ni], 0, 0, 0);
    }
  __syncthreads();  // s1/s2 + vtB reads done
  if (a == b) {  // stage qc[a], vu[a] for the diagonal term1 tile
    stage64<128, 256>(qch + ho + (size_t)(a * 128) * DH, DH, quA, tid);
    stage64<128, 256>(vuh + ho + (size_t)(a * 128) * DH, DH, kuB, tid);
  }
  // D -> LDS transpose (stride 68) over s1 region, then coalesced b128 flush
  {
    f16* epsD = s1;
#pragma unroll
    for (int mi = 0; mi < 2; ++mi)
#pragma unroll
      for (int ni = 0; ni < 4; ++ni)
#pragma unroll
        for (int r = 0; r < 4; ++r)
          epsD[(w * 32 + mi * 16 + q * 4 + r) * 68 + ni * 16 + m] = (f16)dacc[mi][ni][r];
    __syncthreads();
    f16* Dg = DC + ((size_t)hl * 16 + b) * KD + (size_t)(a * 128) * 64;
#pragma unroll
    for (int qq = 0; qq < 4; ++qq) {
      const int idx = qq * 256 + tid, row = idx >> 3, c = idx & 7;
      *(half8*)(Dg + (size_t)row * 64 + c * 8) = *(const half8*)(epsD + row * 68 + c * 8);
    }
  }
  if (a == b) {
    float4v tacc[4][4] = {};
    gemm64(quA, kuB, wm, wn, l, tacc);  // qc[a] . vu[a]^T
    f16* Tg = diagb + ((size_t)hl * 16 + a) * TS;
#pragma unroll
    for (int mi = 0; mi < 4; ++mi)
#pragma unroll
      for (int ni = 0; ni < 4; ++ni)
#pragma unroll
        for (int r = 0; r < 4; ++r) {
          const int row = wm + mi * 16 + q * 4 + r, col = wn + ni * 16 + m;
          Tg[(size_t)row * 128 + col] = (col <= row) ? (f16)tacc[mi][ni][r] : (f16)0.f;
        }
  }
}

// In-place exclusive prefix over T: C^{(T)} = sum_{T'<T} D^{(T')}, f32 accumulate.
// Rows k in tile a are only written by pairs (a,b=T) with T>=a; guard earlier T as 0.
__global__ __launch_bounds__(256) void k_scan(f16* __restrict__ DC, int total) {
  const int idx = blockIdx.x * 256 + threadIdx.x;
  if (idx >= total) return;
  const int g = idx >> 17, off = idx & (KD - 1);
  const int a = off >> 13;  // k-tile of this row
  f16* p = DC + (size_t)g * 16 * KD + off;
  float s = 0.f;
#pragma unroll
  for (int T = 0; T < 16; ++T) {
    const float v = (T >= a) ? (float)p[(size_t)T * KD] : 0.f;
    p[(size_t)T * KD] = (f16)s;
    s += v;
  }
}

// scores(ti,tk) = qc.kc^T - silu( qc.C^{(ti)T} + T1diag(ti) @ sigtile(tk,ti)^T ).
// Flat 112KB staged per block (no K-extent), uniform work, 128 MFMA/wave.
__global__ __launch_bounds__(256) void k_su(const f16* __restrict__ qch, const f16* __restrict__ kch,
                                            const f16* __restrict__ DC, const f16* __restrict__ sigb,
                                            const f16* __restrict__ diagb, f16* __restrict__ scob, int h0) {
  __shared__ __align__(16) f16 L[24576];  // qcA | B1 | B2 ; epilogue (128*LDSH=17408) overlays
  f16* qcA = L; f16* B1 = L + 8192; f16* B2 = L + 16384;
  int ti, tk;
  decode_pair(blockIdx.x, ti, tk);
  const int hl = blockIdx.y;
  const int tid = threadIdx.x, w = tid >> 6, l = tid & 63;
  const int q = l >> 4, m = l & 15;
  const int wm = (w >> 1) * 64, wn = (w & 1) * 64;
  const size_t ho = (size_t)(h0 + hl) * N * DH;

  stage64<128, 256>(qch + ho + (size_t)(ti * 128) * DH, DH, qcA, tid);
  stage64<128, 256>(DC + ((size_t)hl * 16 + ti) * KD + (size_t)(tk * 128) * 64, 64, B1, tid);
  __syncthreads();
  float4v acc[4][4] = {};
  gemm64(qcA, B1, wm, wn, l, acc);  // Su-main = qc[ti] . C^{(ti)}[tk]^T
  const f16* Td = diagb + ((size_t)hl * 16 + ti) * TS;
  const f16* Sg = sigb + ((size_t)hl * NTILES + PU(tk, ti)) * TS;
#pragma unroll
  for (int p = 0; p < 2; ++p) {  // correction: T1diag(ti) @ sigtile^T over j-halves
    __syncthreads();
    stage64<128, 256>(Td + p * 64, 128, B1, tid);
    stage64<128, 256>(Sg + p * 64, 128, B2, tid);
    __syncthreads();
    gemm64(B1, B2, wm, wn, l, acc);
  }
#pragma unroll
  for (int mi = 0; mi < 4; ++mi)
#pragma unroll
    for (int ni = 0; ni < 4; ++ni)
#pragma unroll
      for (int r = 0; r < 4; ++r) {
        const float x = acc[mi][ni][r];
        acc[mi][ni][r] = -(x / (1.f + __expf(-x)));  // -silu(Su)
      }
  __syncthreads();
  stage64<128, 256>(kch + ho + (size_t)(tk * 128) * DH, DH, B1, tid);
  __syncthreads();
  gemm64(qcA, B1, wm, wn, l, acc);  // + Sc
  __syncthreads();
#pragma unroll
  for (int mi = 0; mi < 4; ++mi)
#pragma unroll
    for (int ni = 0; ni < 4; ++ni)
#pragma unroll
      for (int r = 0; r < 4; ++r)
        L[(wm + mi * 16 + q * 4 + r) * LDSH + wn + ni * 16 + m] = (f16)acc[mi][ni][r];
  flush<128, 256>(L, scob + ((size_t)hl * NTILES + PL(ti, tk)) * TS, 128, tid);
}

// Fused softmax(scores) @ vc, flash-style; unchanged from R7.
__global__ __launch_bounds__(256) void k_avs(const f16* __restrict__ scob, const f16* __restrict__ vcT,
                                             f16* __restrict__ Oh, int h0) {
  __shared__ float mlds[4][32], llds[4][32];
  __shared__ __align__(16) float olds[32][68];
  const int mt = 63 - blockIdx.x;
  const int hl = blockIdx.y, h = h0 + hl;
  const int tid = threadIdx.x, w = tid >> 6, l = tid & 63;
  const int q = l >> 4, m = l & 15;
  const f16* Sh = scob + (size_t)hl * NTILES * TS;
  const int titile = mt >> 2, irb = (mt & 3) * 32;
  const f16* V = vcT + (size_t)h * DH * N;
  int vrow[4];
#pragma unroll
  for (int ni = 0; ni < 4; ++ni) vrow[ni] = (ni * 16 + m) * N + q * 8;
  float4v o[2][4] = {};
  float mrun[2] = {-1e30f, -1e30f}, lrun[2] = {0.f, 0.f};
  const int jtmax = mt >> 1;
  for (int jt = w; jt <= jtmax; jt += 4) {
    const int j0 = jt * 64;
    const f16* Sbase = Sh + (size_t)PL(titile, jt >> 1) * TS + (jt & 1) * 64;
    float alphav[2];
    half8 pf[2][2];
#pragma unroll
    for (int mi = 0; mi < 2; ++mi) {
      half8 sf[2];
#pragma unroll
      for (int ks = 0; ks < 2; ++ks)
        sf[ks] = *(const half8*)(Sbase + (irb + mi * 16 + m) * 128 + ks * 32 + q * 8);
      const int rowg = mt * 32 + mi * 16 + m;
      float vals[16];
      float tmx = -1e30f;
#pragma unroll
      for (int ks = 0; ks < 2; ++ks)
#pragma unroll
        for (int e = 0; e < 8; ++e) {
          const int col = j0 + ks * 32 + q * 8 + e;
          const float x = (jt < jtmax || col <= rowg) ? (float)sf[ks][e] : -1e30f;
          vals[ks * 8 + e] = x;
          tmx = fmaxf(tmx, x);
        }
      tmx = fmaxf(tmx, __shfl_xor(tmx, 16));
      tmx = fmaxf(tmx, __shfl_xor(tmx, 32));
      const float nm = fmaxf(mrun[mi], tmx);
      const float al = __expf(mrun[mi] - nm);
      float ts = 0.f;
#pragma unroll
      for (int ks = 0; ks < 2; ++ks)
#pragma unroll
        for (int e = 0; e < 8; ++e) {
          const float p = __expf(vals[ks * 8 + e] - nm);
          pf[mi][ks][e] = (f16)p;
          ts += p;
        }
      ts += __shfl_xor(ts, 16);
      ts += __shfl_xor(ts, 32);
      lrun[mi] = lrun[mi] * al + ts;
      mrun[mi] = nm;
      alphav[mi] = al;
    }
#pragma unroll
    for (int mi = 0; mi < 2; ++mi)
#pragma unroll
      for (int r = 0; r < 4; ++r) {
        const float a = __shfl(alphav[mi], q * 4 + r);
#pragma unroll
        for (int ni = 0; ni < 4; ++ni) o[mi][ni][r] *= a;
      }
#pragma unroll
    for (int ni = 0; ni < 4; ++ni)
#pragma unroll
      for (int ks = 0; ks < 2; ++ks) {
        half8 vf = *(const half8*)(V + vrow[ni] + j0 + ks * 32);
#pragma unroll
        for (int mi = 0; mi < 2; ++mi)
          o[mi][ni] = __builtin_amdgcn_mfma_f32_16x16x32_f16(pf[mi][ks], vf, o[mi][ni], 0, 0, 0);
      }
  }
  if (l < 16)
#pragma unroll
    for (int mi = 0; mi < 2; ++mi) {
      mlds[w][mi * 16 + l] = mrun[mi];
      llds[w][mi * 16 + l] = lrun[mi];
    }
  __syncthreads();
#pragma unroll
  for (int mi = 0; mi < 2; ++mi)
#pragma unroll
    for (int r = 0; r < 4; ++r) {
      const int row = mi * 16 + q * 4 + r;
      const float mstar = fmaxf(fmaxf(mlds[0][row], mlds[1][row]), fmaxf(mlds[2][row], mlds[3][row]));
      const float sw = __expf(mlds[w][row] - mstar);
#pragma unroll
      for (int ni = 0; ni < 4; ++ni) o[mi][ni][r] *= sw;
    }
#pragma unroll
  for (int t = 0; t < 4; ++t) {
    if (w == t) {
#pragma unroll
      for (int mi = 0; mi < 2; ++mi)
#pragma unroll
        for (int ni = 0; ni < 4; ++ni)
#pragma unroll
          for (int r = 0; r < 4; ++r) {
            const int row = mi * 16 + q * 4 + r, col = ni * 16 + m;
            if (t == 0) olds[row][col] = o[mi][ni][r];
            else olds[row][col] += o[mi][ni][r];
          }
    }
    __syncthreads();
  }
  const int row = tid >> 3, c = tid & 7;
  const float mstar = fmaxf(fmaxf(mlds[0][row], mlds[1][row]), fmaxf(mlds[2][row], mlds[3][row]));
  float denom = 0.f;
#pragma unroll
  for (int t = 0; t < 4; ++t) denom += __expf(mlds[t][row] - mstar) * llds[t][row];
  const float inv = 1.f / denom;
  half8 o8;
#pragma unroll
  for (int e = 0; e < 8; ++e) o8[e] = (f16)(olds[row][c * 8 + e] * inv);
  *(half8*)(Oh + (size_t)(mt * 32 + row) * (H * DH) + h * DH + c * 8) = o8;
}

// out = O @ w_out^T, fp32 result.
__global__ __launch_bounds__(256) void k_out(const f16* __restrict__ Oh, const f16* __restrict__ wo,
                                             float* __restrict__ out) {
  __shared__ __align__(16) f16 lds[128 * LDSH];
  f16* As = lds; f16* Bs = lds + 128 * 64;
  const int tid = threadIdx.x, w = tid >> 6, l = tid & 63;
  const int tm = blockIdx.x * 128, tn = blockIdx.y * 128;
  const int wm = (w >> 1) * 64, wn = (w & 1) * 64;
  float4v acc[4][4] = {};
  for (int k0 = 0; k0 < DIM; k0 += 64) {
    stage64<128, 256>(Oh + (size_t)tm * DIM + k0, DIM, As, tid);
    stage64<128, 256>(wo + (size_t)tn * DIM + k0, DIM, Bs, tid);
    __syncthreads();
    gemm64(As, Bs, wm, wn, l, acc);
    __syncthreads();
  }
  const int rbase = (l >> 4) * 4, cidx = l & 15;
#pragma unroll
  for (int mi = 0; mi < 4; ++mi)
#pragma unroll
    for (int ni = 0; ni < 4; ++ni)
#pragma unroll
      for (int r = 0; r < 4; ++r) {
        const int n = tm + wm + mi * 16 + rbase + r;
        const int dmo = tn + wn + ni * 16 + cidx;
        out[(size_t)n * DIM + dmo] = acc[mi][ni][r];
      }
}

extern "C" void kernel_launch(void* const* d_in, const int* in_sizes, int n_in,
                              void* d_out, int out_size, void* d_ws, size_t ws_size,
                              hipStream_t stream) {
  const float* x = (const float*)d_in[0];
  const float* wqkv = (const float*)d_in[1];
  const float* wout = (const float*)d_in[2];
  float* out = (float*)d_out;
  char* ws = (char*)d_ws;

  size_t off = 0;
  auto alloc = [&](size_t b) { size_t o = off; off += (b + 255) & ~(size_t)255; return o; };
  f16* xh  = (f16*)(ws + alloc((size_t)N * DIM * 2));
  f16* wqh = (f16*)(ws + alloc((size_t)F6 * DIM * 2));
  f16* woh = (f16*)(ws + alloc((size_t)DIM * H * DH * 2));
  f16* quh = (f16*)(ws + alloc((size_t)H * N * DH * 2));
  f16* kuh = (f16*)(ws + alloc((size_t)H * N * DH * 2));
  f16* vuh = (f16*)(ws + alloc((size_t)H * N * DH * 2));
  f16* qch = (f16*)(ws + alloc((size_t)H * N * DH * 2));
  f16* kch = (f16*)(ws + alloc((size_t)H * N * DH * 2));
  f16* vcT = (f16*)(ws + alloc((size_t)H * DH * N * 2));
  f16* vuT = (f16*)(ws + alloc((size_t)H * DH * N * 2));
  f16* Oh  = (f16*)(ws + alloc((size_t)N * H * DH * 2));
  const size_t persist = off;

  // per head: sig tiles + D/C + diag tiles + scob tiles (all f16)
  const size_t per_head = ((size_t)NTILES * TS + (size_t)16 * KD + (size_t)16 * TS + (size_t)NTILES * TS) * 2;
  int G = (ws_size > persist + 4096) ? (int)((ws_size - persist - 4096) / per_head) : 1;
  if (G < 1) G = 1;
  if (G > 16) G = 16;
  {  // normalize so rounds are evenly sized
    const int R = (H + G - 1) / G;
    G = (H + R - 1) / R;
  }
  f16* sigb  = (f16*)(ws + alloc((size_t)G * NTILES * TS * 2));
  f16* DC    = (f16*)(ws + alloc((size_t)G * 16 * KD * 2));
  f16* diagb = (f16*)(ws + alloc((size_t)G * 16 * TS * 2));
  f16* scob  = (f16*)(ws + alloc((size_t)G * NTILES * TS * 2));

  k_cast<<<(N * DIM / 4 + 255) / 256, 256, 0, stream>>>(x, xh, N * DIM / 4);
  k_cast<<<(F6 * DIM / 4 + 255) / 256, 256, 0, stream>>>(wqkv, wqh, F6 * DIM / 4);
  k_cast<<<(DIM * H * DH / 4 + 255) / 256, 256, 0, stream>>>(wout, woh, DIM * H * DH / 4);

  k_qkv<<<dim3(N / 128, F6 / 128), 256, 0, stream>>>(xh, wqh, quh, kuh, vuh, qch, kch, vcT, vuT);

  for (int h0 = 0; h0 < H; h0 += G) {
    const int Gr = (H - h0 < G) ? (H - h0) : G;
    k_dsig<<<dim3(136, Gr), 256, 0, stream>>>(quh, kuh, qch, vuh, vuT, sigb, DC, diagb, h0);
    k_scan<<<(Gr * KD + 255) / 256, 256, 0, stream>>>(DC, Gr * KD);
    k_su<<<dim3(136, Gr), 256, 0, stream>>>(qch, kch, DC, sigb, diagb, scob, h0);
    k_avs<<<dim3(64, Gr), 256, 0, stream>>>(scob, vcT, Oh, h0);
  }

  k_out<<<dim3(16, 8), 256, 0, stream>>>(Oh, woh, out);
}

// Round 10
// 322.442 us; speedup vs baseline: 1.6549x; 1.0538x over previous
//
#include <hip/hip_runtime.h>

using f16 = _Float16;
using half8  = __attribute__((ext_vector_type(8))) f16;
using half4v = __attribute__((ext_vector_type(4))) f16;
using float4v = __attribute__((ext_vector_type(4))) float;

#define DEV static __device__ __forceinline__

constexpr int N = 2048, DIM = 1024, H = 16, DH = 64, F6 = 6144;
constexpr int LDSH = 136;       // f16 epilogue row stride (halves)
constexpr int TS = 128 * 128;   // packed tile elements
constexpr int NTILES = 136;     // triangular 128x128 tiles per head
constexpr int KD = 2048 * 64;   // D/C elements per T-slice per head

DEV int PL(int i, int k) { return i * (i + 1) / 2 + k; }                  // lower, k<=i
DEV int PU(int a, int b) { return a * 16 - a * (a - 1) / 2 + (b - a); }   // upper, a<=b

template<int ROWS, int THREADS>
DEV void stage64(const f16* __restrict__ g, int strideHalves, f16* lds, int tid) {
#pragma unroll
  for (int q = 0; q < (ROWS * 8) / THREADS; ++q) {
    const int chunk = q * THREADS + tid;
    const int m = chunk >> 3, c = (chunk & 7) ^ (m & 7);
    const f16* gp = g + (size_t)m * strideHalves + c * 8;
    __builtin_amdgcn_global_load_lds(
        (const __attribute__((address_space(1))) unsigned int*)gp,
        (__attribute__((address_space(3))) unsigned int*)(lds + chunk * 8), 16, 0, 0);
  }
}

DEV half8 rdfrag(const f16* T, int m, int ks, int q) {
  const int c = (ks * 4 + q) ^ (m & 7);
  return *(const half8*)(T + m * 64 + c * 8);
}

// store one element into frag layout (inverse of rdfrag addressing)
DEV void wfrag(f16* T, int row, int col, f16 v) {
  T[row * 64 + ((((col >> 3) ^ (row & 7)) << 3) | (col & 7))] = v;
}

DEV void gemm64(const f16* As, const f16* Bs, int wm, int wn, int l, float4v acc[4][4]) {
  const int q = l >> 4, mm = l & 15;
#pragma unroll
  for (int ks = 0; ks < 2; ++ks) {
    half8 af[4], bf[4];
#pragma unroll
    for (int mi = 0; mi < 4; ++mi) af[mi] = rdfrag(As, wm + mm + mi * 16, ks, q);
#pragma unroll
    for (int ni = 0; ni < 4; ++ni) bf[ni] = rdfrag(Bs, wn + mm + ni * 16, ks, q);
#pragma unroll
    for (int mi = 0; mi < 4; ++mi)
#pragma unroll
      for (int ni = 0; ni < 4; ++ni)
        acc[mi][ni] = __builtin_amdgcn_mfma_f32_16x16x32_f16(af[mi], bf[ni], acc[mi][ni], 0, 0, 0);
  }
}

// p in [0,136) -> (ti,tk), tk<=ti.
DEV void decode_pair(int p, int& ti, int& tk) {
  int t = (int)((sqrtf(8.f * p + 1.f) - 1.f) * 0.5f);
  while (t * (t + 1) / 2 > p) --t;
  while ((t + 1) * (t + 2) / 2 <= p) ++t;
  const int i2 = p - t * (t + 1) / 2;
  ti = (15 - t) + i2;
  tk = i2;
}

__global__ __launch_bounds__(256) void k_cast(const float* __restrict__ s, f16* __restrict__ d, int n4) {
  int i = blockIdx.x * 256 + threadIdx.x;
  if (i < n4) {
    float4 v = ((const float4*)s)[i];
    half4v h;
    h[0] = (f16)v.x; h[1] = (f16)v.y; h[2] = (f16)v.z; h[3] = (f16)v.w;
    ((half4v*)d)[i] = h;
  }
}

// qkvs = x @ w_qkv^T; per-head scatter. vu additionally stored transposed (vuT[h][d][n]).
__global__ __launch_bounds__(256) void k_qkv(const f16* __restrict__ xh, const f16* __restrict__ wh,
                                             f16* __restrict__ quh, f16* __restrict__ kuh,
                                             f16* __restrict__ vuh, f16* __restrict__ qch,
                                             f16* __restrict__ kch, f16* __restrict__ vcT,
                                             f16* __restrict__ vuT) {
  __shared__ __align__(16) f16 lds[128 * LDSH];
  f16* As = lds; f16* Bs = lds + 128 * 64;
  const int tid = threadIdx.x, w = tid >> 6, l = tid & 63;
  const int tm = blockIdx.x * 128, tf = blockIdx.y * 128;
  const int wm = (w >> 1) * 64, wn = (w & 1) * 64;
  float4v acc[4][4] = {};
  for (int k0 = 0; k0 < DIM; k0 += 64) {
    stage64<128, 256>(xh + (size_t)tm * DIM + k0, DIM, As, tid);
    stage64<128, 256>(wh + (size_t)tf * DIM + k0, DIM, Bs, tid);
    __syncthreads();
    gemm64(As, Bs, wm, wn, l, acc);
    __syncthreads();
  }
  const int rbase = (l >> 4) * 4, cidx = l & 15;
  const int t = tf >> 10;
  const float sc = (t == 0 || t == 3) ? 0.125f : 1.f;
  if (t == 5 || t == 2) {
    f16* T = (t == 5) ? vcT : vuT;
#pragma unroll
    for (int mi = 0; mi < 4; ++mi)
#pragma unroll
      for (int ni = 0; ni < 4; ++ni) {
        const int f = tf + wn + ni * 16 + cidx;
        const int h = (f & 1023) >> 6, d = f & 63;
        half4v p;
#pragma unroll
        for (int r = 0; r < 4; ++r) p[r] = (f16)acc[mi][ni][r];
        *(half4v*)(T + ((size_t)h * DH + d) * N + (tm + wm + mi * 16 + rbase)) = p;
      }
  }
  if (t != 5) {
#pragma unroll
    for (int mi = 0; mi < 4; ++mi)
#pragma unroll
      for (int ni = 0; ni < 4; ++ni)
#pragma unroll
        for (int r = 0; r < 4; ++r)
          lds[(wm + mi * 16 + rbase + r) * LDSH + wn + ni * 16 + cidx] = (f16)(acc[mi][ni][r] * sc);
    __syncthreads();
    f16* dst = (t == 0) ? quh : (t == 1) ? kuh : (t == 2) ? vuh : (t == 3) ? qch : kch;
    const int hb = (tf & 1023) >> 6;
#pragma unroll
    for (int q = 0; q < 8; ++q) {
      const int idx = q * 256 + tid, row = idx >> 4, c = idx & 15;
      const int h = hb + (c >> 3), d0 = (c & 7) * 8, n = tm + row;
      *(half8*)(dst + ((size_t)h * N + n) * DH + d0) = *(const half8*)(lds + row * LDSH + c * 8);
    }
  }
}

// Per pair (a<=b): sig tile PU(a,b) = triu1(sigmoid(qu[a].ku[b]^T)), computed ONCE;
// fused D-contribution D^{(b)}[a-rows] = sigtile @ vu[b-block]; for a==b also the
// diagonal term1 tile tril(qc[a].vu[a]^T). Grid (Gr,136): blockIdx.x = head (XCD pin).
__global__ __launch_bounds__(256) void k_dsig(const f16* __restrict__ quh, const f16* __restrict__ kuh,
                                              const f16* __restrict__ qch, const f16* __restrict__ vuh,
                                              const f16* __restrict__ vuT,
                                              f16* __restrict__ sigb, f16* __restrict__ DC,
                                              f16* __restrict__ diagb, int h0) {
  __shared__ __align__(16) f16 L[32768];  // quA 8192 | kuB 8192 (reused vtB0/vtB1) | s1 8192 | s2 8192
  f16* quA = L; f16* kuB = L + 8192; f16* s1 = L + 16384; f16* s2 = L + 24576;
  int b, a;
  decode_pair(blockIdx.y, b, a);
  const int hl = blockIdx.x, h = h0 + hl;
  const int tid = threadIdx.x, w = tid >> 6, l = tid & 63;
  const int q = l >> 4, m = l & 15;
  const int wm = (w >> 1) * 64, wn = (w & 1) * 64;
  const size_t ho = (size_t)h * N * DH;

  stage64<128, 256>(quh + ho + (size_t)(a * 128) * DH, DH, quA, tid);
  stage64<128, 256>(kuh + ho + (size_t)(b * 128) * DH, DH, kuB, tid);
  __syncthreads();
  float4v acc[4][4] = {};
  gemm64(quA, kuB, wm, wn, l, acc);  // qu[a] . ku[b]^T
  __syncthreads();  // quA/kuB reads done
  stage64<64, 256>(vuT + (size_t)h * DH * N + b * 128, N, kuB, tid);
  stage64<64, 256>(vuT + (size_t)h * DH * N + b * 128 + 64, N, kuB + 4096, tid);
  // sigmoid + strict-upper mask -> swizzled A-frag panels s1/s2
#pragma unroll
  for (int mi = 0; mi < 4; ++mi)
#pragma unroll
    for (int ni = 0; ni < 4; ++ni)
#pragma unroll
      for (int r = 0; r < 4; ++r) {
        const int row = wm + mi * 16 + q * 4 + r;   // k-local
        const int col = wn + ni * 16 + m;           // j-local
        const float x = acc[mi][ni][r];
        const f16 sv = (b * 128 + col > a * 128 + row) ? (f16)(1.f / (1.f + __expf(-x))) : (f16)0.f;
        wfrag((col < 64) ? s1 : s2, row, col & 63, sv);
      }
  __syncthreads();  // panels visible; vtB staged
  {
    f16* Sg = sigb + ((size_t)hl * NTILES + PU(a, b)) * TS;
#pragma unroll
    for (int qq = 0; qq < 8; ++qq) {
      const int idx = qq * 256 + tid, row = idx >> 4, c = idx & 15;
      const f16* p = ((c >> 3) ? s2 : s1) + row * 64 + (((c & 7) ^ (row & 7)) << 3);
      *(half8*)(Sg + (size_t)row * 128 + c * 8) = *(const half8*)p;
    }
  }
  float4v dacc[2][4] = {};
#pragma unroll
  for (int p = 0; p < 2; ++p)
#pragma unroll
    for (int ks = 0; ks < 2; ++ks) {
      half8 bf[4], af[2];
#pragma unroll
      for (int ni = 0; ni < 4; ++ni) bf[ni] = rdfrag(kuB + p * 4096, ni * 16 + m, ks, q);
#pragma unroll
      for (int mi = 0; mi < 2; ++mi) af[mi] = rdfrag(p ? s2 : s1, w * 32 + mi * 16 + m, ks, q);
#pragma unroll
      for (int mi = 0; mi < 2; ++mi)
#pragma unroll
        for (int ni = 0; ni < 4; ++ni)
          dacc[mi][ni] = __builtin_amdgcn_mfma_f32_16x16x32_f16(af[mi], bf[ni], dacc[mi][ni], 0, 0, 0);
    }
  __syncthreads();
  if (a == b) {
    stage64<128, 256>(qch + ho + (size_t)(a * 128) * DH, DH, quA, tid);
    stage64<128, 256>(vuh + ho + (size_t)(a * 128) * DH, DH, kuB, tid);
  }
  {
    f16* epsD = s1;
#pragma unroll
    for (int mi = 0; mi < 2; ++mi)
#pragma unroll
      for (int ni = 0; ni < 4; ++ni)
#pragma unroll
        for (int r = 0; r < 4; ++r)
          epsD[(w * 32 + mi * 16 + q * 4 + r) * 68 + ni * 16 + m] = (f16)dacc[mi][ni][r];
    __syncthreads();
    f16* Dg = DC + ((size_t)hl * 16 + b) * KD + (size_t)(a * 128) * 64;
#pragma unroll
    for (int qq = 0; qq < 4; ++qq) {
      const int idx = qq * 256 + tid, row = idx >> 3, c = idx & 7;
      *(half8*)(Dg + (size_t)row * 64 + c * 8) = *(const half8*)(epsD + row * 68 + c * 8);
    }
  }
  if (a == b) {
    float4v tacc[4][4] = {};
    gemm64(quA, kuB, wm, wn, l, tacc);  // qc[a] . vu[a]^T
    f16* Tg = diagb + ((size_t)hl * 16 + a) * TS;
#pragma unroll
    for (int mi = 0; mi < 4; ++mi)
#pragma unroll
      for (int ni = 0; ni < 4; ++ni)
#pragma unroll
        for (int r = 0; r < 4; ++r) {
          const int row = wm + mi * 16 + q * 4 + r, col = wn + ni * 16 + m;
          Tg[(size_t)row * 128 + col] = (col <= row) ? (f16)tacc[mi][ni][r] : (f16)0.f;
        }
  }
}

// In-place exclusive prefix over T: C^{(T)} = sum_{T'<T} D^{(T')}, f32 accumulate.
__global__ __launch_bounds__(256) void k_scan(f16* __restrict__ DC, int total) {
  const int idx = blockIdx.x * 256 + threadIdx.x;
  if (idx >= total) return;
  const int g = idx >> 17, off = idx & (KD - 1);
  const int a = off >> 13;
  f16* p = DC + (size_t)g * 16 * KD + off;
  float s = 0.f;
#pragma unroll
  for (int T = 0; T < 16; ++T) {
    const float v = (T >= a) ? (float)p[(size_t)T * KD] : 0.f;
    p[(size_t)T * KD] = (f16)s;
    s += v;
  }
}

// Fused scores + online-softmax + PV. Block = (head hl = blockIdx.x [XCD pin],
// 32-row tile mt). 4 waves split 64-col jt-chunks (disjoint work -> register-direct
// B-frag loads are free; no LDS staging, no barriers in the main loop).
// Per chunk: s = qc.C^T + T1d.sig^T ; s := -silu(s) ; s += qc.kc^T ; mask diag;
// online softmax in C-layout (rows=q*4+r -> alpha rescale is register-direct);
// P transposed to A-layout via wave-private swizzled LDS; PV MFMA with vcT.
__global__ __launch_bounds__(256) void k_favs(const f16* __restrict__ qch, const f16* __restrict__ kch,
                                              const f16* __restrict__ DC, const f16* __restrict__ sigb,
                                              const f16* __restrict__ diagb, const f16* __restrict__ vcT,
                                              f16* __restrict__ Oh, int h0) {
  __shared__ float mlds[4][32], llds[4][32];
  __shared__ __align__(16) float olds[32][68];
  __shared__ __align__(16) f16 plds[4][32 * 64];
  const int hl = blockIdx.x, h = h0 + hl;
  const int mt = 63 - (int)blockIdx.y;  // longest-first
  const int tid = threadIdx.x, w = tid >> 6, l = tid & 63;
  const int q = l >> 4, m = l & 15;
  const int ti = mt >> 2, r0 = mt * 32;
  const size_t ho = (size_t)h * N * DH;
  const f16* qc = qch + ho;
  const f16* kc = kch + ho;
  const f16* Cb = DC + ((size_t)hl * 16 + ti) * KD;
  const f16* Td = diagb + ((size_t)hl * 16 + ti) * TS;
  const f16* Sgb = sigb + (size_t)hl * NTILES * TS;
  const f16* V = vcT + (size_t)h * DH * N;
  f16* pw = plds[w];

  // cached A-frags: qc rows [r0,r0+32) and T1diag rows (local) [dr,dr+32) x 128 j
  half8 qcA[2][2], tdA[2][4];
  const int dr = (mt & 3) * 32;
#pragma unroll
  for (int mi = 0; mi < 2; ++mi) {
#pragma unroll
    for (int ks = 0; ks < 2; ++ks)
      qcA[mi][ks] = *(const half8*)(qc + (size_t)(r0 + mi * 16 + m) * DH + ks * 32 + q * 8);
#pragma unroll
    for (int ks = 0; ks < 4; ++ks)
      tdA[mi][ks] = *(const half8*)(Td + (size_t)(dr + mi * 16 + m) * 128 + ks * 32 + q * 8);
  }

  float4v o[2][4] = {};
  float mrun[2][4], lrun[2][4];
#pragma unroll
  for (int mi = 0; mi < 2; ++mi)
#pragma unroll
    for (int r = 0; r < 4; ++r) { mrun[mi][r] = -1e30f; lrun[mi][r] = 0.f; }

  const int jtmax = mt >> 1;
  for (int jt = w; jt <= jtmax; jt += 4) {
    const int k0 = jt * 64;
    const int tkt = jt >> 1, koff = (jt & 1) * 64;
    const f16* Sg = Sgb + (size_t)PU(tkt, ti) * TS;
    float4v s[2][4] = {};
    // phase 1: qc . C^{(ti)}[k]^T  (K=64)
#pragma unroll
    for (int ks = 0; ks < 2; ++ks) {
      half8 bf[4];
#pragma unroll
      for (int ni = 0; ni < 4; ++ni)
        bf[ni] = *(const half8*)(Cb + (size_t)(k0 + ni * 16 + m) * 64 + ks * 32 + q * 8);
#pragma unroll
      for (int mi = 0; mi < 2; ++mi)
#pragma unroll
        for (int ni = 0; ni < 4; ++ni)
          s[mi][ni] = __builtin_amdgcn_mfma_f32_16x16x32_f16(qcA[mi][ks], bf[ni], s[mi][ni], 0, 0, 0);
    }
    // phase 2: + T1diag . sig^T  (K=128)
#pragma unroll
    for (int ks = 0; ks < 4; ++ks) {
      half8 bf[4];
#pragma unroll
      for (int ni = 0; ni < 4; ++ni)
        bf[ni] = *(const half8*)(Sg + (size_t)(koff + ni * 16 + m) * 128 + ks * 32 + q * 8);
#pragma unroll
      for (int mi = 0; mi < 2; ++mi)
#pragma unroll
        for (int ni = 0; ni < 4; ++ni)
          s[mi][ni] = __builtin_amdgcn_mfma_f32_16x16x32_f16(tdA[mi][ks], bf[ni], s[mi][ni], 0, 0, 0);
    }
    // s := -silu(Su)
#pragma unroll
    for (int mi = 0; mi < 2; ++mi)
#pragma unroll
      for (int ni = 0; ni < 4; ++ni)
#pragma unroll
        for (int r = 0; r < 4; ++r) {
          const float x = s[mi][ni][r];
          s[mi][ni][r] = -(x / (1.f + __expf(-x)));
        }
    // phase 3: + Sc = qc . kc^T  (K=64)
#pragma unroll
    for (int ks = 0; ks < 2; ++ks) {
      half8 bf[4];
#pragma unroll
      for (int ni = 0; ni < 4; ++ni)
        bf[ni] = *(const half8*)(kc + (size_t)(k0 + ni * 16 + m) * DH + ks * 32 + q * 8);
#pragma unroll
      for (int mi = 0; mi < 2; ++mi)
#pragma unroll
        for (int ni = 0; ni < 4; ++ni)
          s[mi][ni] = __builtin_amdgcn_mfma_f32_16x16x32_f16(qcA[mi][ks], bf[ni], s[mi][ni], 0, 0, 0);
    }
    // causal mask (only the diagonal chunk has cols > some rows)
    if (jt == jtmax) {
#pragma unroll
      for (int mi = 0; mi < 2; ++mi)
#pragma unroll
        for (int ni = 0; ni < 4; ++ni) {
          const int col = k0 + ni * 16 + m;
#pragma unroll
          for (int r = 0; r < 4; ++r)
            if (col > r0 + mi * 16 + q * 4 + r) s[mi][ni][r] = -1e30f;
        }
    }
    // online softmax (C-layout: rows = mi*16 + q*4 + r)
    float al[2][4], ts[2][4];
#pragma unroll
    for (int mi = 0; mi < 2; ++mi)
#pragma unroll
      for (int r = 0; r < 4; ++r) {
        float tmx = fmaxf(fmaxf(s[mi][0][r], s[mi][1][r]), fmaxf(s[mi][2][r], s[mi][3][r]));
#pragma unroll
        for (int x = 1; x < 16; x <<= 1) tmx = fmaxf(tmx, __shfl_xor(tmx, x));
        const float nm = fmaxf(mrun[mi][r], tmx);
        al[mi][r] = __expf(mrun[mi][r] - nm);
        mrun[mi][r] = nm;
        ts[mi][r] = 0.f;
      }
#pragma unroll
    for (int mi = 0; mi < 2; ++mi)
#pragma unroll
      for (int ni = 0; ni < 4; ++ni)
#pragma unroll
        for (int r = 0; r < 4; ++r) {
          const float p = __expf(s[mi][ni][r] - mrun[mi][r]);
          wfrag(pw, mi * 16 + q * 4 + r, ni * 16 + m, (f16)p);
          ts[mi][r] += p;
        }
#pragma unroll
    for (int mi = 0; mi < 2; ++mi)
#pragma unroll
      for (int r = 0; r < 4; ++r) {
#pragma unroll
        for (int x = 1; x < 16; x <<= 1) ts[mi][r] += __shfl_xor(ts[mi][r], x);
        lrun[mi][r] = lrun[mi][r] * al[mi][r] + ts[mi][r];
#pragma unroll
        for (int ni = 0; ni < 4; ++ni) o[mi][ni][r] *= al[mi][r];
      }
    // PV: O += P(A-layout via LDS) . vc(B from vcT)
#pragma unroll
    for (int ks = 0; ks < 2; ++ks) {
      half8 af[2], bf[4];
#pragma unroll
      for (int mi = 0; mi < 2; ++mi) af[mi] = rdfrag(pw, mi * 16 + m, ks, q);
#pragma unroll
      for (int ni = 0; ni < 4; ++ni)
        bf[ni] = *(const half8*)(V + (size_t)(ni * 16 + m) * N + k0 + ks * 32 + q * 8);
#pragma unroll
      for (int mi = 0; mi < 2; ++mi)
#pragma unroll
        for (int ni = 0; ni < 4; ++ni)
          o[mi][ni] = __builtin_amdgcn_mfma_f32_16x16x32_f16(af[mi], bf[ni], o[mi][ni], 0, 0, 0);
    }
  }
  // merge the 4 waves
  if (m == 0)
#pragma unroll
    for (int mi = 0; mi < 2; ++mi)
#pragma unroll
      for (int r = 0; r < 4; ++r) {
        mlds[w][mi * 16 + q * 4 + r] = mrun[mi][r];
        llds[w][mi * 16 + q * 4 + r] = lrun[mi][r];
      }
  __syncthreads();
#pragma unroll
  for (int mi = 0; mi < 2; ++mi)
#pragma unroll
    for (int r = 0; r < 4; ++r) {
      const int row = mi * 16 + q * 4 + r;
      const float mstar = fmaxf(fmaxf(mlds[0][row], mlds[1][row]), fmaxf(mlds[2][row], mlds[3][row]));
      const float sw = __expf(mlds[w][row] - mstar);
#pragma unroll
      for (int ni = 0; ni < 4; ++ni) o[mi][ni][r] *= sw;
    }
#pragma unroll
  for (int t = 0; t < 4; ++t) {
    if (w == t) {
#pragma unroll
      for (int mi = 0; mi < 2; ++mi)
#pragma unroll
        for (int ni = 0; ni < 4; ++ni)
#pragma unroll
          for (int r = 0; r < 4; ++r) {
            const int row = mi * 16 + q * 4 + r, col = ni * 16 + m;
            if (t == 0) olds[row][col] = o[mi][ni][r];
            else olds[row][col] += o[mi][ni][r];
          }
    }
    __syncthreads();
  }
  const int row = tid >> 3, c = tid & 7;
  const float mstar = fmaxf(fmaxf(mlds[0][row], mlds[1][row]), fmaxf(mlds[2][row], mlds[3][row]));
  float denom = 0.f;
#pragma unroll
  for (int t = 0; t < 4; ++t) denom += __expf(mlds[t][row] - mstar) * llds[t][row];
  const float inv = 1.f / denom;
  half8 o8;
#pragma unroll
  for (int e = 0; e < 8; ++e) o8[e] = (f16)(olds[row][c * 8 + e] * inv);
  *(half8*)(Oh + (size_t)(mt * 32 + row) * (H * DH) + h * DH + c * 8) = o8;
}

// out = O @ w_out^T, fp32 result.
__global__ __launch_bounds__(256) void k_out(const f16* __restrict__ Oh, const f16* __restrict__ wo,
                                             float* __restrict__ out) {
  __shared__ __align__(16) f16 lds[128 * LDSH];
  f16* As = lds; f16* Bs = lds + 128 * 64;
  const int tid = threadIdx.x, w = tid >> 6, l = tid & 63;
  const int tm = blockIdx.x * 128, tn = blockIdx.y * 128;
  const int wm = (w >> 1) * 64, wn = (w & 1) * 64;
  float4v acc[4][4] = {};
  for (int k0 = 0; k0 < DIM; k0 += 64) {
    stage64<128, 256>(Oh + (size_t)tm * DIM + k0, DIM, As, tid);
    stage64<128, 256>(wo + (size_t)tn * DIM + k0, DIM, Bs, tid);
    __syncthreads();
    gemm64(As, Bs, wm, wn, l, acc);
    __syncthreads();
  }
  const int rbase = (l >> 4) * 4, cidx = l & 15;
#pragma unroll
  for (int mi = 0; mi < 4; ++mi)
#pragma unroll
    for (int ni = 0; ni < 4; ++ni)
#pragma unroll
      for (int r = 0; r < 4; ++r) {
        const int n = tm + wm + mi * 16 + rbase + r;
        const int dmo = tn + wn + ni * 16 + cidx;
        out[(size_t)n * DIM + dmo] = acc[mi][ni][r];
      }
}

extern "C" void kernel_launch(void* const* d_in, const int* in_sizes, int n_in,
                              void* d_out, int out_size, void* d_ws, size_t ws_size,
                              hipStream_t stream) {
  const float* x = (const float*)d_in[0];
  const float* wqkv = (const float*)d_in[1];
  const float* wout = (const float*)d_in[2];
  float* out = (float*)d_out;
  char* ws = (char*)d_ws;

  size_t off = 0;
  auto alloc = [&](size_t b) { size_t o = off; off += (b + 255) & ~(size_t)255; return o; };
  f16* xh  = (f16*)(ws + alloc((size_t)N * DIM * 2));
  f16* wqh = (f16*)(ws + alloc((size_t)F6 * DIM * 2));
  f16* woh = (f16*)(ws + alloc((size_t)DIM * H * DH * 2));
  f16* quh = (f16*)(ws + alloc((size_t)H * N * DH * 2));
  f16* kuh = (f16*)(ws + alloc((size_t)H * N * DH * 2));
  f16* vuh = (f16*)(ws + alloc((size_t)H * N * DH * 2));
  f16* qch = (f16*)(ws + alloc((size_t)H * N * DH * 2));
  f16* kch = (f16*)(ws + alloc((size_t)H * N * DH * 2));
  f16* vcT = (f16*)(ws + alloc((size_t)H * DH * N * 2));
  f16* vuT = (f16*)(ws + alloc((size_t)H * DH * N * 2));
  f16* Oh  = (f16*)(ws + alloc((size_t)N * H * DH * 2));
  const size_t persist = off;

  // per head: sig tiles + D/C + diag tiles (scob eliminated by k_favs fusion)
  const size_t per_head = ((size_t)NTILES * TS + (size_t)16 * KD + (size_t)16 * TS) * 2;
  int G = (ws_size > persist + 4096) ? (int)((ws_size - persist - 4096) / per_head) : 1;
  if (G < 1) G = 1;
  if (G > 16) G = 16;
  {  // normalize so rounds are evenly sized (prefer G=8 for head->XCD pinning)
    const int R = (H + G - 1) / G;
    G = (H + R - 1) / R;
  }
  f16* sigb  = (f16*)(ws + alloc((size_t)G * NTILES * TS * 2));
  f16* DC    = (f16*)(ws + alloc((size_t)G * 16 * KD * 2));
  f16* diagb = (f16*)(ws + alloc((size_t)G * 16 * TS * 2));

  k_cast<<<(N * DIM / 4 + 255) / 256, 256, 0, stream>>>(x, xh, N * DIM / 4);
  k_cast<<<(F6 * DIM / 4 + 255) / 256, 256, 0, stream>>>(wqkv, wqh, F6 * DIM / 4);
  k_cast<<<(DIM * H * DH / 4 + 255) / 256, 256, 0, stream>>>(wout, woh, DIM * H * DH / 4);

  k_qkv<<<dim3(N / 128, F6 / 128), 256, 0, stream>>>(xh, wqh, quh, kuh, vuh, qch, kch, vcT, vuT);

  for (int h0 = 0; h0 < H; h0 += G) {
    const int Gr = (H - h0 < G) ? (H - h0) : G;
    k_dsig<<<dim3(Gr, 136), 256, 0, stream>>>(quh, kuh, qch, vuh, vuT, sigb, DC, diagb, h0);
    k_scan<<<(Gr * KD + 255) / 256, 256, 0, stream>>>(DC, Gr * KD);
    k_favs<<<dim3(Gr, 64), 256, 0, stream>>>(qch, kch, DC, sigb, diagb, vcT, Oh, h0);
  }

  k_out<<<dim3(16, 8), 256, 0, stream>>>(Oh, woh, out);
}